// Round 4
// baseline (341.668 us; speedup 1.0000x reference)
//
#include <hip/hip_runtime.h>
#include <hip/hip_bf16.h>

// ElasticMLP fused: 8 layers, H=128, B=262144, relu each layer, skip(+x) for l>0.
//
// Round-6 structure: ZERO LDS, ZERO barriers — h lives in registers.
//  - MFMA 32x32x16 bf16, wave-tile M=128 (all neurons) x N=32 batch rows.
//    Each wave owns its 32 batch rows for the whole 8-layer chain; blocks/waves
//    are fully independent instruction streams (latency-bound fix: rounds 0-5
//    all plateaued 10-14k cyc/layer on barrier lockstep vs ~2.5k of work).
//  - Layer-to-layer handoff in-register: C/D layout (col=lane&31,
//    row=(reg&3)+8*(reg>>2)+4*hi) -> next B-frag (col=lane&31, k=8*hi+e) via
//    4x cvt_pk_bf16 + 2x v_permlane32_swap_b32 per 16-k slice (T12 machinery):
//      pa = pack(own A-part), pb = pack(own B-part); swap(pa.hi, pb.lo)
//      => pa' = B-frag d0/d1 (hi=0: own A, hi=1: partner B)
//         pb' = B-frag d2/d3 (hi=0: partner A, hi=1: own B)   [lane-verified]
//  - h0 built from xr (x already loaded in C-layout for skip-adds) by the same
//    helper — no extra loads. Final layer: relu+skip straight to dwordx4 stores.
//  - W pre-swizzled by wconv into FRAGMENT-MAJOR order: chunk
//    ((l*4+mi)*8+kk)*64+lane holds W[l][32mi+(lane&31)][16kk+8*(lane>>5)+0..7],
//    so each A-frag load is ONE coalesced 1KB global_load_dwordx4, identical
//    for all waves -> L1/L2 broadcast-hot. 2-deep software prefetch in k.
//  - VGPR ~220 (xr 64 + acc 64 + hf 32 + af 32 + misc) fits __launch_bounds__
//    (256,2) => 2 waves/SIMD. Rounds 3/5 load-sinking was budget-misfit (128);
//    here the pipeline fits the 256 budget.
// Roofline: HBM 268 MB => ~43 us floor; MFMA pipe ~7 us; VALU ~12 us.

typedef __bf16 bf16_t;
typedef __bf16 bf16x8 __attribute__((ext_vector_type(8)));
typedef float floatx4 __attribute__((ext_vector_type(4)));
typedef float floatx16 __attribute__((ext_vector_type(16)));
typedef unsigned int uintx4 __attribute__((ext_vector_type(4)));

#define HID 128
#define NLAYERS 8

// pack two f32 -> dword of 2 bf16 (lo=a, hi=b); compiler pairs casts to v_cvt_pk
static __device__ __forceinline__ unsigned pk(float a, float b) {
    union { bf16_t h[2]; unsigned u; } r;
    r.h[0] = (bf16_t)a; r.h[1] = (bf16_t)b;
    return r.u;
}
// v_permlane32_swap_b32: a.hi-lanes <-> b.lo-lanes
static __device__ __forceinline__ void plswap(unsigned& a, unsigned& b) {
    asm volatile("v_permlane32_swap_b32 %0, %1" : "+v"(a), "+v"(b));
}

// W [8][128][128] f32 -> fragment-major bf16 chunks (16B each):
// chunk t = ((l*4+mi)*8+kk)*64+lane  ->  W[l][32mi+(lane&31)][16kk+8*(lane>>5)+0..7]
__global__ __launch_bounds__(256) void wconv_kernel(const float* __restrict__ w,
                                                    bf16_t* __restrict__ wb) {
    int t = blockIdx.x * 256 + threadIdx.x;      // 16384 chunks => 64 blocks
    int lane = t & 63, kk = (t >> 6) & 7, mi = (t >> 9) & 3, l = t >> 11;
    int row = 32*mi + (lane & 31);
    int col = 16*kk + 8*(lane >> 5);
    const float* src = w + ((l*HID + row)*HID + col);
    floatx4 v0 = *(const floatx4*)src;
    floatx4 v1 = *(const floatx4*)(src + 4);
    bf16x8 o = { (bf16_t)v0[0], (bf16_t)v0[1], (bf16_t)v0[2], (bf16_t)v0[3],
                 (bf16_t)v1[0], (bf16_t)v1[1], (bf16_t)v1[2], (bf16_t)v1[3] };
    *(bf16x8*)(wb + (long)t * 8) = o;
}

__global__ __launch_bounds__(256, 2) void mlp_kernel(
    const float* __restrict__ x, const bf16_t* __restrict__ wb,
    const float* __restrict__ bias, float* __restrict__ out)
{
    const int tid  = threadIdx.x;
    const int lane = tid & 63;
    const int col  = lane & 31;          // batch col within wave stripe; C col
    const int hi4  = (lane >> 5) * 4;    // C row offset of lane half
    const long row = (long)blockIdx.x * 128 + (tid >> 6) * 32 + col;
    const float* xrow = x + row * HID;

    // x in C-fragment layout: xr[mi][g] = x[row][32mi+8g+hi4 .. +3]
    floatx4 xr[4][4];
#pragma unroll
    for (int mi = 0; mi < 4; ++mi)
#pragma unroll
      for (int g = 0; g < 4; ++g)
        xr[mi][g] = *(const floatx4*)&xrow[32*mi + 8*g + hi4];

    // h0 = bf16(x) in B-frag layout, built in-register from xr
    bf16x8 hf[8];
#pragma unroll
    for (int kk = 0; kk < 8; ++kk) {
        const int mi = kk >> 1, h2 = (kk & 1) * 2;
        floatx4 A = xr[mi][h2], B = xr[mi][h2 + 1];
        unsigned pa0 = pk(A[0], A[1]), pa1 = pk(A[2], A[3]);
        unsigned pb0 = pk(B[0], B[1]), pb1 = pk(B[2], B[3]);
        plswap(pa0, pb0); plswap(pa1, pb1);
        uintx4 u = { pa0, pa1, pb0, pb1 };
        hf[kk] = __builtin_bit_cast(bf16x8, u);
    }

    const bf16x8* wbv = (const bf16x8*)wb;   // frag-major chunks

    for (int l = 0; l < NLAYERS; ++l) {
        // acc init = bias (C layout): acc[mi][4g+j] = bias[l][32mi+8g+hi4+j]
        floatx16 acc[4];
#pragma unroll
        for (int mi = 0; mi < 4; ++mi)
#pragma unroll
          for (int g = 0; g < 4; ++g) {
            floatx4 bv = *(const floatx4*)&bias[l*HID + 32*mi + 8*g + hi4];
            acc[mi][4*g+0] = bv[0]; acc[mi][4*g+1] = bv[1];
            acc[mi][4*g+2] = bv[2]; acc[mi][4*g+3] = bv[3];
          }

        // K = 128 in 8 steps of 16; A-frags from global, coalesced 1KB/instr,
        // 2-deep software prefetch (fits the 256-VGPR budget).
        const long lbase = (long)l * 32;     // layer chunk base / 64
        bf16x8 af0[4], af1[4];
#pragma unroll
        for (int mi = 0; mi < 4; ++mi) af0[mi] = wbv[(lbase + mi*8 + 0)*64 + lane];
#pragma unroll
        for (int mi = 0; mi < 4; ++mi) af1[mi] = wbv[(lbase + mi*8 + 1)*64 + lane];
#pragma unroll
        for (int kk = 0; kk < 8; ++kk) {
            bf16x8 acur[4];
#pragma unroll
            for (int mi = 0; mi < 4; ++mi) acur[mi] = (kk & 1) ? af1[mi] : af0[mi];
            if (kk + 2 < 8) {
#pragma unroll
                for (int mi = 0; mi < 4; ++mi) {
                    bf16x8 v = wbv[(lbase + mi*8 + kk + 2)*64 + lane];
                    if (kk & 1) af1[mi] = v; else af0[mi] = v;
                }
            }
#pragma unroll
            for (int mi = 0; mi < 4; ++mi)
                acc[mi] = __builtin_amdgcn_mfma_f32_32x32x16_bf16(
                              acur[mi], hf[kk], acc[mi], 0, 0, 0);
        }

        if (l < NLAYERS - 1) {
            // h' = relu(acc) (+x for l>0) -> next-layer B-frags, in-register
#pragma unroll
            for (int kk = 0; kk < 8; ++kk) {
                const int mi = kk >> 1, hh = kk & 1;
                float s[8];
#pragma unroll
                for (int j = 0; j < 4; ++j) {
                    float va = fmaxf(acc[mi][8*hh + j],     0.0f);
                    float vb = fmaxf(acc[mi][8*hh + 4 + j], 0.0f);
                    if (l > 0) { va += xr[mi][2*hh][j]; vb += xr[mi][2*hh+1][j]; }
                    s[j] = va; s[4 + j] = vb;
                }
                unsigned pa0 = pk(s[0], s[1]), pa1 = pk(s[2], s[3]);
                unsigned pb0 = pk(s[4], s[5]), pb1 = pk(s[6], s[7]);
                plswap(pa0, pb0); plswap(pa1, pb1);
                uintx4 u = { pa0, pa1, pb0, pb1 };
                hf[kk] = __builtin_bit_cast(bf16x8, u);
            }
        } else {
            // last layer: relu + skip, fp32 dwordx4 stores (C layout == xr layout)
            float* orow = out + row * HID;
#pragma unroll
            for (int mi = 0; mi < 4; ++mi)
#pragma unroll
              for (int g = 0; g < 4; ++g) {
                floatx4 o;
#pragma unroll
                for (int j = 0; j < 4; ++j)
                    o[j] = fmaxf(acc[mi][4*g + j], 0.0f) + xr[mi][g][j];
                *(floatx4*)&orow[32*mi + 8*g + hi4] = o;
              }
        }
    }
}

extern "C" void kernel_launch(void* const* d_in, const int* in_sizes, int n_in,
                              void* d_out, int out_size, void* d_ws, size_t ws_size,
                              hipStream_t stream) {
    const float* x = (const float*)d_in[0];    // 262144*128
    const float* w = (const float*)d_in[1];    // 8*128*128
    const float* b = (const float*)d_in[2];    // 8*128
    float* out = (float*)d_out;
    bf16_t* wb = (bf16_t*)d_ws;                // 131072 bf16 = 256 KB scratch

    wconv_kernel<<<NLAYERS*HID*HID/(256*8), 256, 0, stream>>>(w, wb);   // 64 blocks

    const int nblocks = 262144 / 128;          // 2048 (4 waves x 32 rows each)
    mlp_kernel<<<nblocks, 256, 0, stream>>>(x, wb, b, out);
}

// Round 5
// 291.538 us; speedup vs baseline: 1.1719x; 1.1719x over previous
//
#include <hip/hip_runtime.h>
#include <hip/hip_bf16.h>

// ElasticMLP fused: 8 layers, H=128, B=262144, relu each layer, skip(+x) for l>0.
//
// Round-7 = round-0 (proven 136 us) with TM 128->64 for 3 blocks/CU.
// Evidence: r6 (barrier-free) and r5 (high-occupancy, reg-starved) both lost to
// r0 -> kernel is latency-bound on the per-wave layer chain, and r0's
// LDS-W + reg-prefetch structure is the only one the compiler holds without
// load-sinking. So: keep r0's structure byte-for-byte, shrink the batch tile.
//  - TM=64 rows/block, 4 waves, wave-tile M=64 x N=32: acc[4][2] (32 VGPR),
//    xr[4][2] (32), wreg[8] (32), bnext[4] (16) => ~135 VGPR, cap 170 via
//    __launch_bounds__(256,3).
//  - LDS: hs[64][136] (17,408 B) + wsh[128][136] (34,816 B) = 52,224 B
//    => 3 blocks/CU = 12 waves/CU (+50% latency-hiding vs r0's 8).
//  - W path unchanged: global->wreg (prefetched during layer l's MFMAs)
//    ->ds_write at layer l+1 start. 2 barriers/layer, single-buffer hs.
// MFMA roles: A = W (m = neuron), B = h (n = batch); C gives each lane 4
// consecutive neurons of one batch row -> b64 LDS writebacks, dwordx4
// x-loads/out-stores. Bias folded into acc init. LDH=136 (272 B stride):
// 16B-aligned, 2-way-max bank aliasing on b128/b64 (free on CDNA4).

typedef __bf16 bf16_t;
typedef __bf16 bf16x8 __attribute__((ext_vector_type(8)));
typedef __bf16 bf16x4 __attribute__((ext_vector_type(4)));
typedef float floatx4 __attribute__((ext_vector_type(4)));

#define HID 128
#define NLAYERS 8
#define TM 64           // batch rows per block
#define LDH 136         // LDS row stride (bf16 elems)

__global__ __launch_bounds__(256) void wconv_kernel(const float* __restrict__ w,
                                                    bf16_t* __restrict__ wb) {
    int i = (blockIdx.x * 256 + threadIdx.x) * 4;   // 131072 elems / 4 => 128 blocks
    floatx4 v = *(const floatx4*)&w[i];
    bf16x4 o = { (bf16_t)v[0], (bf16_t)v[1], (bf16_t)v[2], (bf16_t)v[3] };
    *(bf16x4*)&wb[i] = o;
}

__global__ __launch_bounds__(256, 3) void mlp_kernel(
    const float* __restrict__ x, const bf16_t* __restrict__ wb,
    const float* __restrict__ bias, float* __restrict__ out)
{
    __shared__ __align__(16) bf16_t hs[TM][LDH];    // activations [batch][i], 17,408 B
    __shared__ __align__(16) bf16_t wsh[HID][LDH];  // current layer W [j][i], 34,816 B

    const int tid  = threadIdx.x;
    const int wave = tid >> 6;
    const int lane = tid & 63;
    const int c16  = lane & 15;        // A/B frag row index; C col (batch)
    const int quad = lane >> 4;        // k-group; C row group (neuron)
    const int m0 = (wave >> 1) * 64;   // neuron offset of wave quadrant (0/64)
    const int n0 = (wave & 1) * 32;    // batch offset of wave quadrant (0/32)
    const long rowbase = (long)blockIdx.x * TM;
    const int jb = m0 + quad * 4;      // neuron base for this lane (+ mi*16)

    // --- x in C-fragment layout: xr[mi][ni] = x[batch=n0+ni*16+c16][jb+mi*16 .. +3]
    floatx4 xr[4][2];
#pragma unroll
    for (int ni = 0; ni < 2; ++ni) {
        const float* xrow = x + (rowbase + n0 + ni*16 + c16) * HID;
#pragma unroll
        for (int mi = 0; mi < 4; ++mi)
            xr[mi][ni] = *(const floatx4*)&xrow[jb + mi*16];
    }
    // --- h0 = bf16(x): 4 consecutive neurons per write => b64 writes
#pragma unroll
    for (int ni = 0; ni < 2; ++ni) {
        bf16_t* hrow = &hs[n0 + ni*16 + c16][0];
#pragma unroll
        for (int mi = 0; mi < 4; ++mi) {
            floatx4 v = xr[mi][ni];
            bf16x4 o = { (bf16_t)v[0], (bf16_t)v[1], (bf16_t)v[2], (bf16_t)v[3] };
            *(bf16x4*)&hrow[jb + mi*16] = o;
        }
    }

    // --- prefetch layer-0 weights (regs) + bias frags
    const bf16x8* wbv = (const bf16x8*)wb;   // 2048 16B-chunks per layer
    bf16x8 wreg[8];
#pragma unroll
    for (int p = 0; p < 8; ++p) wreg[p] = wbv[p*256 + tid];
    floatx4 bnext[4];
#pragma unroll
    for (int mi = 0; mi < 4; ++mi) bnext[mi] = *(const floatx4*)&bias[jb + mi*16];

    for (int l = 0; l < NLAYERS; ++l) {
        // stage W_l regs -> LDS (prev layer's reads fenced by the post-read sync)
#pragma unroll
        for (int p = 0; p < 8; ++p) {
            int f = p*256 + tid;                    // 16 chunks per W row
            *(bf16x8*)&wsh[f >> 4][(f & 15) * 8] = wreg[p];
        }
        __syncthreads();   // wsh staged; hs(l) writes visible

        // acc init = bias (before bnext is overwritten by the prefetch)
        floatx4 acc[4][2];
#pragma unroll
        for (int mi = 0; mi < 4; ++mi)
#pragma unroll
          for (int ni = 0; ni < 2; ++ni)
            acc[mi][ni] = bnext[mi];

        // prefetch next layer's W + bias during this layer's MFMAs
        if (l + 1 < NLAYERS) {
#pragma unroll
            for (int p = 0; p < 8; ++p) wreg[p] = wbv[(l+1)*2048 + p*256 + tid];
#pragma unroll
            for (int mi = 0; mi < 4; ++mi)
                bnext[mi] = *(const floatx4*)&bias[(l+1)*HID + jb + mi*16];
        }

        // K = 128 in 4 steps of 32
#pragma unroll
        for (int k = 0; k < 4; ++k) {
            const int kc = k*32 + quad*8;
            bf16x8 af[4], bfr[2];
#pragma unroll
            for (int mi = 0; mi < 4; ++mi)
                af[mi] = *(const bf16x8*)&wsh[m0 + mi*16 + c16][kc];   // A = W
#pragma unroll
            for (int ni = 0; ni < 2; ++ni)
                bfr[ni] = *(const bf16x8*)&hs[n0 + ni*16 + c16][kc];   // B = h
#pragma unroll
            for (int mi = 0; mi < 4; ++mi)
#pragma unroll
              for (int ni = 0; ni < 2; ++ni)
                acc[mi][ni] = __builtin_amdgcn_mfma_f32_16x16x32_bf16(
                                  af[mi], bfr[ni], acc[mi][ni], 0, 0, 0);
        }
        __syncthreads();   // all hs/wsh frag reads done

        if (l < NLAYERS - 1) {
            // h' = relu(acc) (+x for l>0), packed b64 writes
#pragma unroll
            for (int ni = 0; ni < 2; ++ni) {
                bf16_t* hrow = &hs[n0 + ni*16 + c16][0];
#pragma unroll
                for (int mi = 0; mi < 4; ++mi) {
                    floatx4 v = acc[mi][ni];
                    float s0 = fmaxf(v[0], 0.0f), s1 = fmaxf(v[1], 0.0f);
                    float s2 = fmaxf(v[2], 0.0f), s3 = fmaxf(v[3], 0.0f);
                    if (l > 0) {
                        floatx4 xv = xr[mi][ni];
                        s0 += xv[0]; s1 += xv[1]; s2 += xv[2]; s3 += xv[3];
                    }
                    bf16x4 o = { (bf16_t)s0, (bf16_t)s1, (bf16_t)s2, (bf16_t)s3 };
                    *(bf16x4*)&hrow[jb + mi*16] = o;
                }
            }
        } else {
            // last layer: relu + skip, fp32 dwordx4 stores
#pragma unroll
            for (int ni = 0; ni < 2; ++ni) {
                float* orow = out + (rowbase + n0 + ni*16 + c16) * HID;
#pragma unroll
                for (int mi = 0; mi < 4; ++mi) {
                    floatx4 v = acc[mi][ni];
                    floatx4 xv = xr[mi][ni];
                    floatx4 o;
                    o[0] = fmaxf(v[0], 0.0f) + xv[0];
                    o[1] = fmaxf(v[1], 0.0f) + xv[1];
                    o[2] = fmaxf(v[2], 0.0f) + xv[2];
                    o[3] = fmaxf(v[3], 0.0f) + xv[3];
                    *(floatx4*)&orow[jb + mi*16] = o;
                }
            }
        }
    }
}

extern "C" void kernel_launch(void* const* d_in, const int* in_sizes, int n_in,
                              void* d_out, int out_size, void* d_ws, size_t ws_size,
                              hipStream_t stream) {
    const float* x = (const float*)d_in[0];    // 262144*128
    const float* w = (const float*)d_in[1];    // 8*128*128
    const float* b = (const float*)d_in[2];    // 8*128
    float* out = (float*)d_out;
    bf16_t* wb = (bf16_t*)d_ws;                // 131072 bf16 = 256 KB scratch

    wconv_kernel<<<NLAYERS*HID*HID/(256*4), 256, 0, stream>>>(w, wb);

    const int nblocks = 262144 / TM;           // 4096
    mlp_kernel<<<nblocks, 256, 0, stream>>>(x, wb, b, out);
}

// Round 6
// 284.329 us; speedup vs baseline: 1.2017x; 1.0254x over previous
//
#include <hip/hip_runtime.h>
#include <hip/hip_bf16.h>

// ElasticMLP fused: 8 layers, H=128, B=262144, relu each layer, skip(+x) for l>0.
//
// Round-8: r7 geometry (TM=64, 3 blocks/CU) with the W path moved to
// global_load_lds — ZERO registers in the W pipeline.
// Diagnosis r3/r5/r6/r7: every W-prefetch held in VGPRs across the layer loop
// gets sunk by the scheduler (r7: VGPR=84, wreg gone, exposed L2 stalls).
// Fix: global->LDS DMA (no VGPR roundtrip, nothing to sink).
//  - wconv writes W in FRAGMENT-MAJOR chunk order:
//      chunk c = (l*32 + H*16 + k*4 + mi)*64 + lane holds
//      W[l][H*64 + mi*16 + (lane&15)][k*32 + (lane>>4)*8 .. +7]  (bf16x8, 16B)
//    => staging = 8x global_load_lds_dwordx4/thread, LDS dst = uniform base
//       + lane*16 (the HW pattern, m104); af reads are linear 16B/lane,
//       conflict-free, wsh needs NO padding (32 KB exactly).
//  - Staging for W_{l+1} issues right after the post-read barrier; its L2
//    latency hides under the ~600cy epilogue; the compiler's vmcnt(0) before
//    the next barrier lands after that work.
//  - LDS: hs[64][136] (17,408) + wsh_lin (32,768) = 50,176 B => 3 blocks/CU,
//    12 waves/CU. VGPR ~ acc32+xr32+bnext16+transients ~ 120 (cap 170).
// MFMA roles: A = W (m = neuron), B = h (n = batch); 16x16x32 bf16; wave-tile
// M=64 x N=32 (m0=(wave>>1)*64, n0=(wave&1)*32). Bias folded into acc init.
// hs LDH=136 (272 B stride): 16B-aligned, 2-way-max bank aliasing (free).

typedef __bf16 bf16_t;
typedef __bf16 bf16x8 __attribute__((ext_vector_type(8)));
typedef __bf16 bf16x4 __attribute__((ext_vector_type(4)));
typedef float floatx4 __attribute__((ext_vector_type(4)));

#define HID 128
#define NLAYERS 8
#define TM 64           // batch rows per block
#define LDH 136         // hs row stride (bf16 elems)

#define GLOAD_LDS16(g, l)  __builtin_amdgcn_global_load_lds(                 \
    (__attribute__((address_space(1))) void*)(g),                            \
    (__attribute__((address_space(3))) void*)(l), 16, 0, 0)

// W [8][128][128] f32 -> fragment-major bf16 chunks (16B each).
__global__ __launch_bounds__(256) void wconv_kernel(const float* __restrict__ w,
                                                    bf16_t* __restrict__ wb) {
    int t = blockIdx.x * 256 + threadIdx.x;      // 16384 chunks => 64 blocks
    int lane = t & 63;
    int f    = (t >> 6) & 31;                    // frag id within layer
    int l    = t >> 11;
    int H  = f >> 4, k = (f >> 2) & 3, mi = f & 3;
    int row = H*64 + mi*16 + (lane & 15);
    int col = k*32 + (lane >> 4) * 8;
    const float* src = w + ((l*HID + row)*HID + col);
    floatx4 v0 = *(const floatx4*)src;
    floatx4 v1 = *(const floatx4*)(src + 4);
    bf16x8 o = { (bf16_t)v0[0], (bf16_t)v0[1], (bf16_t)v0[2], (bf16_t)v0[3],
                 (bf16_t)v1[0], (bf16_t)v1[1], (bf16_t)v1[2], (bf16_t)v1[3] };
    *(bf16x8*)(wb + (long)t * 8) = o;
}

__global__ __launch_bounds__(256, 3) void mlp_kernel(
    const float* __restrict__ x, const bf16_t* __restrict__ wb,
    const float* __restrict__ bias, float* __restrict__ out)
{
    __shared__ __align__(16) bf16_t hs[TM][LDH];      // activations, 17,408 B
    __shared__ __align__(16) bf16_t wsh[HID*HID];     // frag-major W_l, 32,768 B

    const int tid  = threadIdx.x;
    const int wave = tid >> 6;
    const int lane = tid & 63;
    const int c16  = lane & 15;        // A/B frag row index; C col (batch)
    const int quad = lane >> 4;        // k-group; C row group (neuron)
    const int m0 = (wave >> 1) * 64;   // neuron offset of wave quadrant (0/64)
    const int H  = wave >> 1;          // W frag half
    const int n0 = (wave & 1) * 32;    // batch offset of wave quadrant (0/32)
    const long rowbase = (long)blockIdx.x * TM;
    const int jb = m0 + quad * 4;      // neuron base for this lane (+ mi*16)

    // --- stage W_0 first: DMA runs under the x-load/h0 prologue
#pragma unroll
    for (int p = 0; p < 8; ++p) {
        const bf16_t* src = wb + (long)(p*256 + wave*64 + lane) * 8;
        GLOAD_LDS16(src, &wsh[(p*256 + wave*64) * 8]);
    }

    // --- x in C-fragment layout: xr[mi][ni] = x[batch=n0+ni*16+c16][jb+mi*16 .. +3]
    floatx4 xr[4][2];
#pragma unroll
    for (int ni = 0; ni < 2; ++ni) {
        const float* xrow = x + (rowbase + n0 + ni*16 + c16) * HID;
#pragma unroll
        for (int mi = 0; mi < 4; ++mi)
            xr[mi][ni] = *(const floatx4*)&xrow[jb + mi*16];
    }
    // --- h0 = bf16(x): 4 consecutive neurons per write => b64 writes
#pragma unroll
    for (int ni = 0; ni < 2; ++ni) {
        bf16_t* hrow = &hs[n0 + ni*16 + c16][0];
#pragma unroll
        for (int mi = 0; mi < 4; ++mi) {
            floatx4 v = xr[mi][ni];
            bf16x4 o = { (bf16_t)v[0], (bf16_t)v[1], (bf16_t)v[2], (bf16_t)v[3] };
            *(bf16x4*)&hrow[jb + mi*16] = o;
        }
    }

    floatx4 bnext[4];
#pragma unroll
    for (int mi = 0; mi < 4; ++mi) bnext[mi] = *(const floatx4*)&bias[jb + mi*16];

    __syncthreads();   // W_0 staged (vmcnt drained), h0 visible

    for (int l = 0; l < NLAYERS; ++l) {
        // acc init = bias (before bnext is overwritten by the prefetch)
        floatx4 acc[4][2];
#pragma unroll
        for (int mi = 0; mi < 4; ++mi)
#pragma unroll
          for (int ni = 0; ni < 2; ++ni)
            acc[mi][ni] = bnext[mi];

        if (l + 1 < NLAYERS) {
#pragma unroll
            for (int mi = 0; mi < 4; ++mi)
                bnext[mi] = *(const floatx4*)&bias[(l+1)*HID + jb + mi*16];
        }

        // K = 128 in 4 steps of 32; af from frag-major wsh (linear, conflict-free)
#pragma unroll
        for (int k = 0; k < 4; ++k) {
            const int kc = k*32 + quad*8;
            bf16x8 af[4], bfr[2];
#pragma unroll
            for (int mi = 0; mi < 4; ++mi)
                af[mi] = *(const bf16x8*)&wsh[((H*16 + k*4 + mi)*64 + lane) * 8];
#pragma unroll
            for (int ni = 0; ni < 2; ++ni)
                bfr[ni] = *(const bf16x8*)&hs[n0 + ni*16 + c16][kc];   // B = h
#pragma unroll
            for (int mi = 0; mi < 4; ++mi)
#pragma unroll
              for (int ni = 0; ni < 2; ++ni)
                acc[mi][ni] = __builtin_amdgcn_mfma_f32_16x16x32_bf16(
                                  af[mi], bfr[ni], acc[mi][ni], 0, 0, 0);
        }
        __syncthreads();   // all wsh/hs frag reads done

        if (l < NLAYERS - 1) {
            // issue W_{l+1} DMA now: L2 latency hides under the epilogue below
#pragma unroll
            for (int p = 0; p < 8; ++p) {
                const bf16_t* src = wb + (long)((l+1)*2048 + p*256 + wave*64 + lane) * 8;
                GLOAD_LDS16(src, &wsh[(p*256 + wave*64) * 8]);
            }
            // h' = relu(acc) (+x for l>0), packed b64 writes
#pragma unroll
            for (int ni = 0; ni < 2; ++ni) {
                bf16_t* hrow = &hs[n0 + ni*16 + c16][0];
#pragma unroll
                for (int mi = 0; mi < 4; ++mi) {
                    floatx4 v = acc[mi][ni];
                    float s0 = fmaxf(v[0], 0.0f), s1 = fmaxf(v[1], 0.0f);
                    float s2 = fmaxf(v[2], 0.0f), s3 = fmaxf(v[3], 0.0f);
                    if (l > 0) {
                        floatx4 xv = xr[mi][ni];
                        s0 += xv[0]; s1 += xv[1]; s2 += xv[2]; s3 += xv[3];
                    }
                    bf16x4 o = { (bf16_t)s0, (bf16_t)s1, (bf16_t)s2, (bf16_t)s3 };
                    *(bf16x4*)&hrow[jb + mi*16] = o;
                }
            }
            __syncthreads();   // W_{l+1} staged (vmcnt drained), h' visible
        } else {
            // last layer: relu + skip, fp32 dwordx4 stores
#pragma unroll
            for (int ni = 0; ni < 2; ++ni) {
                float* orow = out + (rowbase + n0 + ni*16 + c16) * HID;
#pragma unroll
                for (int mi = 0; mi < 4; ++mi) {
                    floatx4 v = acc[mi][ni];
                    floatx4 xv = xr[mi][ni];
                    floatx4 o;
                    o[0] = fmaxf(v[0], 0.0f) + xv[0];
                    o[1] = fmaxf(v[1], 0.0f) + xv[1];
                    o[2] = fmaxf(v[2], 0.0f) + xv[2];
                    o[3] = fmaxf(v[3], 0.0f) + xv[3];
                    *(floatx4*)&orow[jb + mi*16] = o;
                }
            }
        }
    }
}

extern "C" void kernel_launch(void* const* d_in, const int* in_sizes, int n_in,
                              void* d_out, int out_size, void* d_ws, size_t ws_size,
                              hipStream_t stream) {
    const float* x = (const float*)d_in[0];    // 262144*128
    const float* w = (const float*)d_in[1];    // 8*128*128
    const float* b = (const float*)d_in[2];    // 8*128
    float* out = (float*)d_out;
    bf16_t* wb = (bf16_t*)d_ws;                // 131072 bf16 = 256 KB scratch

    wconv_kernel<<<NLAYERS*HID*HID/(256*8), 256, 0, stream>>>(w, wb);   // 64 blocks

    const int nblocks = 262144 / TM;           // 4096
    mlp_kernel<<<nblocks, 256, 0, stream>>>(x, wb, b, out);
}